// Round 3
// baseline (1346.125 us; speedup 1.0000x reference)
//
#include <hip/hip_runtime.h>
#include <cstdint>

#define KT 9408      // K_TOTAL
#define NT 512       // o-tile per block
#define KC 16        // k sub-chunk staged in LDS

// ---------------------------------------------------------------------------
// Partial GEMM:  partial[s][b][o] = sum_{k in split s} X[b,k] * W[o,k]
// Dual-source: concatenated K = K1 (X1,W1) then K2 (X2,W2). M = 32 fixed.
// Block: 256 threads, o-tile NT=512, thread register tile = 8 b x 8 o.
// Caller guarantees: Ktot % ksplit == 0 and (Ktot/ksplit) % KC == 0.
// W loads: float4 f = p*256+t -> row r=f>>2, col4=(f&3)*4: 4 consecutive lanes
// cover one row's 64B span -> 16 lines per wave-inst (was 64).
// Register-prefetch double buffer hides HBM latency under the FMA block.
// ---------------------------------------------------------------------------
__global__ __launch_bounds__(256, 3) void gemm32_partial(
    const float* __restrict__ X1, const float* __restrict__ W1, int K1,
    const float* __restrict__ X2, const float* __restrict__ W2, int K2,
    float* __restrict__ partial, int O, int ksplit)
{
    __shared__ float Xs[KC][32];     // [k_local][b]
    __shared__ float Wt[KC][NT];     // [k_local][o_local] transposed

    const int t      = threadIdx.x;
    const int o0     = blockIdx.x * NT;
    const int s      = blockIdx.y;
    const int Ktot   = K1 + K2;
    const int kchunk = Ktot / ksplit;          // multiple of KC
    const int kbeg   = s * kchunk;
    const int kend   = kbeg + kchunk;
    const int lane_o = t & 63;
    const int tb     = t >> 6;                 // wave id -> b-group (8 b's)

    float4 wbuf[8];
    float  xbuf[2];

    auto loadW = [&](int kc0) {
#pragma unroll
        for (int p = 0; p < 8; ++p) {
            int f  = p * 256 + t;      // 0..2047
            int r  = f >> 2;           // 0..511
            int c4 = (f & 3) << 2;     // 0,4,8,12
            int o  = o0 + r;
            int kg = kc0 + c4;
            float4 v = make_float4(0.f, 0.f, 0.f, 0.f);
            if (o < O)
                v = (kg < K1) ? *(const float4*)&W1[(size_t)o * K1 + kg]
                              : *(const float4*)&W2[(size_t)o * K2 + (kg - K1)];
            wbuf[p] = v;
        }
    };
    auto loadX = [&](int kc0) {
#pragma unroll
        for (int it = 0; it < 2; ++it) {
            int idx = t + 256 * it;    // 0..511
            int c   = idx >> 5;
            int bb  = idx & 31;
            int kg  = kc0 + c;
            xbuf[it] = (kg < K1) ? X1[(size_t)bb * K1 + kg]
                                 : X2[(size_t)bb * K2 + (kg - K1)];
        }
    };

    float acc[8][8];
#pragma unroll
    for (int bi = 0; bi < 8; bi++)
#pragma unroll
        for (int j = 0; j < 8; j++) acc[bi][j] = 0.f;

    loadW(kbeg);
    loadX(kbeg);

    for (int kc0 = kbeg; kc0 < kend; kc0 += KC) {
        // ---- commit prefetched regs to LDS (compiler inserts vmcnt wait)
#pragma unroll
        for (int it = 0; it < 2; ++it) {
            int idx = t + 256 * it;
            Xs[idx >> 5][idx & 31] = xbuf[it];
        }
#pragma unroll
        for (int p = 0; p < 8; ++p) {
            int f  = p * 256 + t;
            int r  = f >> 2;
            int c4 = (f & 3) << 2;
            Wt[c4 + 0][r] = wbuf[p].x;
            Wt[c4 + 1][r] = wbuf[p].y;
            Wt[c4 + 2][r] = wbuf[p].z;
            Wt[c4 + 3][r] = wbuf[p].w;
        }
        __syncthreads();

        // ---- issue next chunk's loads; they fly during the FMA block
        if (kc0 + KC < kend) { loadW(kc0 + KC); loadX(kc0 + KC); }

        // ---- compute: KC k-steps x (8b x 8o) FMAs
#pragma unroll
        for (int c = 0; c < KC; c++) {
            float4 xa = *(const float4*)&Xs[c][tb * 8];       // wave-broadcast
            float4 xb = *(const float4*)&Xs[c][tb * 8 + 4];
            float xv[8] = {xa.x, xa.y, xa.z, xa.w, xb.x, xb.y, xb.z, xb.w};
            float w[8];
#pragma unroll
            for (int j = 0; j < 8; j++) w[j] = Wt[c][lane_o + 64 * j];
#pragma unroll
            for (int bi = 0; bi < 8; bi++)
#pragma unroll
                for (int j = 0; j < 8; j++) acc[bi][j] += xv[bi] * w[j];
        }
        __syncthreads();
    }

    // ---- store partials (coalesced over o)
#pragma unroll
    for (int bi = 0; bi < 8; bi++) {
        int b = tb * 8 + bi;
#pragma unroll
        for (int j = 0; j < 8; j++) {
            int o = o0 + lane_o + 64 * j;
            if (o < O)
                partial[((size_t)s * 32 + b) * O + o] = acc[bi][j];
        }
    }
}

// ---------------------------------------------------------------------------
// Reduce K-split partials + bias(es) + optional ReLU.  Y is [32][O] row-major.
// ---------------------------------------------------------------------------
__global__ __launch_bounds__(256) void reduce_bias(
    const float* __restrict__ partial, const float* __restrict__ bias1,
    const float* __restrict__ bias2, float* __restrict__ Y, int O, int relu,
    int ksplit)
{
    int idx = blockIdx.x * 256 + threadIdx.x;
    if (idx >= 32 * O) return;
    int b = idx / O, o = idx - b * O;
    float s = bias1[o] + (bias2 ? bias2[o] : 0.f);
    for (int k = 0; k < ksplit; k++)
        s += partial[((size_t)k * 32 + b) * O + o];
    Y[idx] = relu ? fmaxf(s, 0.f) : s;
}

// ---------------------------------------------------------------------------
// Fused per-pixel conv chain. One thread = one pixel. Weights are block-
// uniform (sample = blockIdx.y) -> scalar s_loads. The hidden vector h[64]
// lives in LDS (per-thread float4 slots, no barrier needed) so the register
// live-set stays ~60-80 VGPRs -> no scratch spills.
// ks layout per sample: k_in[64*32] | k_mid[64*64] | k_out[32*64] |
//                       k_short[32*32] | b_in[64] | b_mid[64] | b_out[32] | b_short[32]
// ---------------------------------------------------------------------------
__global__ __launch_bounds__(256, 2) void conv_fused(
    const float* __restrict__ x, const float* __restrict__ ks,
    float* __restrict__ out)
{
    __shared__ float4 hls[16][256];   // h[q] at hls[q>>2][t][q&3], 64 KB

    const int t = threadIdx.x;
    const int b = blockIdx.y;
    const int p = blockIdx.x * 256 + t;             // 0..16383
    const float* __restrict__ kb = ks + (size_t)b * KT;
    const float* __restrict__ xb = x + (size_t)b * 32 * 16384 + p;

    float xv[32];
#pragma unroll
    for (int i = 0; i < 32; i++) xv[i] = xb[(size_t)i * 16384];

    // ---- layer in: h = relu(k_in @ x + b_in), streamed to LDS in float4s
    for (int q4 = 0; q4 < 16; ++q4) {
        float4 hq;
        float* hqf = (float*)&hq;
#pragma unroll
        for (int j = 0; j < 4; ++j) {
            int oo = q4 * 4 + j;
            float a = kb[9216 + oo];
#pragma unroll
            for (int i = 0; i < 32; i++) a += kb[oo * 32 + i] * xv[i];
            hqf[j] = fmaxf(a, 0.f);
        }
        hls[q4][t] = hq;
    }

    // ---- shortcut + out-bias accumulators: o_ = k_short @ x + b_short + b_out
    float o_[32];
#pragma unroll
    for (int oo = 0; oo < 32; oo++) {
        float a = kb[9376 + oo] + kb[9344 + oo];
#pragma unroll
        for (int i = 0; i < 32; i++) a += kb[8192 + oo * 32 + i] * xv[i];
        o_[oo] = a;
    }

    // ---- mid layer (chunks of 8, h from LDS) fused into out accumulation
#pragma unroll 1
    for (int c = 0; c < 64; c += 8) {
        float m[8];
#pragma unroll
        for (int j = 0; j < 8; j++) m[j] = kb[9280 + c + j];
#pragma unroll 1
        for (int q4 = 0; q4 < 16; ++q4) {
            float4 hq = hls[q4][t];
            const float* hqf = (const float*)&hq;
#pragma unroll
            for (int j = 0; j < 8; j++)
#pragma unroll
                for (int e = 0; e < 4; ++e)
                    m[j] += kb[2048 + (c + j) * 64 + q4 * 4 + e] * hqf[e];
        }
#pragma unroll
        for (int j = 0; j < 8; j++) m[j] = fmaxf(m[j], 0.f);
#pragma unroll
        for (int oo = 0; oo < 32; oo++) {
            float a = o_[oo];
#pragma unroll
            for (int j = 0; j < 8; j++) a += kb[6144 + oo * 64 + c + j] * m[j];
            o_[oo] = a;
        }
    }

#pragma unroll
    for (int oo = 0; oo < 32; oo++)
        out[((size_t)b * 32 + oo) * 16384 + p] = o_[oo];
}

// ---------------------------------------------------------------------------
extern "C" void kernel_launch(void* const* d_in, const int* in_sizes, int n_in,
                              void* d_out, int out_size, void* d_ws, size_t ws_size,
                              hipStream_t stream)
{
    const float* x   = (const float*)d_in[0];
    const float* lat = (const float*)d_in[1];
    const float* w0  = (const float*)d_in[2];
    const float* b0  = (const float*)d_in[3];
    const float* w1a = (const float*)d_in[4];
    const float* b1a = (const float*)d_in[5];
    const float* w1b = (const float*)d_in[6];
    const float* b1b = (const float*)d_in[7];
    const float* w1s = (const float*)d_in[8];
    const float* b1s = (const float*)d_in[9];
    const float* w2a = (const float*)d_in[10];
    const float* b2a = (const float*)d_in[11];
    const float* w2b = (const float*)d_in[12];
    const float* b2b = (const float*)d_in[13];
    const float* w2s = (const float*)d_in[14];
    const float* b2s = (const float*)d_in[15];
    const float* wfa = (const float*)d_in[16];
    const float* bfa = (const float*)d_in[17];

    // intermediates in d_ws (~2.8 MB)
    float* ws  = (float*)d_ws;
    float* h0  = ws;               // 32*512
    float* t1  = ws + 16384;       // 32*1024
    float* h1  = ws + 49152;       // 32*512
    float* t2  = ws + 65536;       // 32*1024
    float* h2  = ws + 98304;       // 32*9408
    float* ksb = ws + 399360;      // 32*9408
    // K-split partials live in d_out (<=33.7 MB < 64 MB); conv overwrites at end.
    float* pbuf = (float*)d_out;

    dim3 blk(256);
    auto g  = [](int O, int ks) { return dim3((unsigned)((O + NT - 1) / NT), (unsigned)ks); };
    auto rg = [](int O) { return dim3((unsigned)((32 * O + 255) / 256)); };

    // h0 = lat @ w0.T + b0                      (K=512, split 32 -> chunk 16)
    gemm32_partial<<<g(512, 32), blk, 0, stream>>>(lat, w0, 512, nullptr, nullptr, 0, pbuf, 512, 32);
    reduce_bias<<<rg(512), blk, 0, stream>>>(pbuf, b0, nullptr, h0, 512, 0, 32);
    // t1 = relu(h0 @ w1a.T + b1a)               (K=512)
    gemm32_partial<<<g(1024, 32), blk, 0, stream>>>(h0, w1a, 512, nullptr, nullptr, 0, pbuf, 1024, 32);
    reduce_bias<<<rg(1024), blk, 0, stream>>>(pbuf, b1a, nullptr, t1, 1024, 1, 32);
    // h1 = h0 @ w1s.T + b1s + t1 @ w1b.T + b1b  (K=1536, split 32 -> chunk 48)
    gemm32_partial<<<g(512, 32), blk, 0, stream>>>(h0, w1s, 512, t1, w1b, 1024, pbuf, 512, 32);
    reduce_bias<<<rg(512), blk, 0, stream>>>(pbuf, b1s, b1b, h1, 512, 0, 32);
    // t2 = relu(h1 @ w2a.T + b2a)               (K=512)
    gemm32_partial<<<g(1024, 32), blk, 0, stream>>>(h1, w2a, 512, nullptr, nullptr, 0, pbuf, 1024, 32);
    reduce_bias<<<rg(1024), blk, 0, stream>>>(pbuf, b2a, nullptr, t2, 1024, 1, 32);
    // h2 = h1 @ w2s.T + b2s + t2 @ w2b.T + b2b  (K=1536, split 32 -> chunk 48)
    gemm32_partial<<<g(KT, 32), blk, 0, stream>>>(h1, w2s, 512, t2, w2b, 1024, pbuf, KT, 32);
    reduce_bias<<<rg(KT), blk, 0, stream>>>(pbuf, b2s, b2b, h2, KT, 0, 32);
    // ks = h2 @ wfa.T + bfa                     (K=9408, split 28 -> chunk 336)
    gemm32_partial<<<g(KT, 28), blk, 0, stream>>>(h2, wfa, KT, nullptr, nullptr, 0, pbuf, KT, 28);
    reduce_bias<<<rg(KT), blk, 0, stream>>>(pbuf, bfa, nullptr, ksb, KT, 0, 28);

    // fused per-sample 1x1 conv chain
    conv_fused<<<dim3(64, 32), blk, 0, stream>>>(x, ksb, (float*)d_out);
}

// Round 4
// 609.325 us; speedup vs baseline: 2.2092x; 2.2092x over previous
//
#include <hip/hip_runtime.h>
#include <cstdint>

#define KT 9408      // K_TOTAL
#define NT 256       // o-tile per block
#define KC 16        // k sub-chunk staged in LDS

// ---------------------------------------------------------------------------
// Partial GEMM:  partial[s][b][o] = sum_{k in split s} X[b,k] * W[o,k]
// Dual-source: concatenated K = K1 (X1,W1) then K2 (X2,W2). M = 32 fixed.
// Block: 256 threads. Per-thread tile 8b x 4o (acc = 32 VGPRs, no spills).
// Caller guarantees: (K1+K2) % ksplit == 0 and ((K1+K2)/ksplit) % KC == 0.
// W staging: float4 f = p*256+t -> row r=f>>2, col4=(f&3)*4: 4 consecutive
// lanes cover one row's 64B -> 16 x 64B segments per wave-inst.
// Small register prefetch (4 float4 + 2 float) hides HBM latency under FMAs.
// ---------------------------------------------------------------------------
__global__ __launch_bounds__(256, 1) void gemm32_partial(
    const float* __restrict__ X1, const float* __restrict__ W1, int K1,
    const float* __restrict__ X2, const float* __restrict__ W2, int K2,
    float* __restrict__ partial, int O, int ksplit)
{
    __shared__ float Xs[KC][32];     // [k_local][b]
    __shared__ float Wt[KC][NT];     // [k_local][o_local] transposed

    const int t      = threadIdx.x;
    const int o0     = blockIdx.x * NT;
    const int s      = blockIdx.y;
    const int kchunk = (K1 + K2) / ksplit;     // multiple of KC
    const int kbeg   = s * kchunk;
    const int kend   = kbeg + kchunk;
    const int lane   = t & 63;
    const int wv     = t >> 6;                 // wave id -> b-group (8 b's)

    // W-staging address components (constant over chunks)
    const int sr  = t >> 2;                    // 0..63  (+64*p)
    const int sc4 = (t & 3) << 2;              // 0,4,8,12

    float4 wpre[4];
    float  xpre[2];

    // ---- prefetch first chunk
    {
        int kc0 = kbeg;
#pragma unroll
        for (int p = 0; p < 4; ++p) {
            int r = sr + 64 * p;
            int o = o0 + r;
            int kg = kc0 + sc4;
            float4 v = make_float4(0.f, 0.f, 0.f, 0.f);
            if (o < O)
                v = (kg < K1) ? *(const float4*)&W1[(size_t)o * K1 + kg]
                              : *(const float4*)&W2[(size_t)o * K2 + (kg - K1)];
            wpre[p] = v;
        }
#pragma unroll
        for (int it = 0; it < 2; ++it) {
            int idx = t + 256 * it;
            int kg  = kc0 + (idx >> 5);
            int bb  = idx & 31;
            xpre[it] = (kg < K1) ? X1[(size_t)bb * K1 + kg]
                                 : X2[(size_t)bb * K2 + (kg - K1)];
        }
    }

    float acc[8][4];
#pragma unroll
    for (int bi = 0; bi < 8; bi++)
#pragma unroll
        for (int j = 0; j < 4; j++) acc[bi][j] = 0.f;

    for (int kc0 = kbeg; kc0 < kend; kc0 += KC) {
        // ---- commit prefetched regs to LDS
#pragma unroll
        for (int it = 0; it < 2; ++it) {
            int idx = t + 256 * it;
            Xs[idx >> 5][idx & 31] = xpre[it];
        }
#pragma unroll
        for (int p = 0; p < 4; ++p) {
            int r = sr + 64 * p;
            Wt[sc4 + 0][r] = wpre[p].x;
            Wt[sc4 + 1][r] = wpre[p].y;
            Wt[sc4 + 2][r] = wpre[p].z;
            Wt[sc4 + 3][r] = wpre[p].w;
        }
        __syncthreads();

        // ---- issue next chunk's loads; they fly during the FMA block
        if (kc0 + KC < kend) {
            int kn = kc0 + KC;
#pragma unroll
            for (int p = 0; p < 4; ++p) {
                int r = sr + 64 * p;
                int o = o0 + r;
                int kg = kn + sc4;
                float4 v = make_float4(0.f, 0.f, 0.f, 0.f);
                if (o < O)
                    v = (kg < K1) ? *(const float4*)&W1[(size_t)o * K1 + kg]
                                  : *(const float4*)&W2[(size_t)o * K2 + (kg - K1)];
                wpre[p] = v;
            }
#pragma unroll
            for (int it = 0; it < 2; ++it) {
                int idx = t + 256 * it;
                int kg  = kn + (idx >> 5);
                int bb  = idx & 31;
                xpre[it] = (kg < K1) ? X1[(size_t)bb * K1 + kg]
                                     : X2[(size_t)bb * K2 + (kg - K1)];
            }
        }

        // ---- compute: KC k-steps x (8b x 4o) FMAs
#pragma unroll
        for (int c = 0; c < KC; c++) {
            float4 xa = *(const float4*)&Xs[c][wv * 8];       // wave-broadcast
            float4 xb = *(const float4*)&Xs[c][wv * 8 + 4];
            float xv[8] = {xa.x, xa.y, xa.z, xa.w, xb.x, xb.y, xb.z, xb.w};
            float w[4];
#pragma unroll
            for (int j = 0; j < 4; j++) w[j] = Wt[c][lane + 64 * j];
#pragma unroll
            for (int bi = 0; bi < 8; bi++)
#pragma unroll
                for (int j = 0; j < 4; j++) acc[bi][j] += xv[bi] * w[j];
        }
        __syncthreads();
    }

    // ---- store partials (coalesced over o)
#pragma unroll
    for (int bi = 0; bi < 8; bi++) {
        int b = wv * 8 + bi;
#pragma unroll
        for (int j = 0; j < 4; j++) {
            int o = o0 + lane + 64 * j;
            if (o < O)
                partial[((size_t)s * 32 + b) * O + o] = acc[bi][j];
        }
    }
}

// ---------------------------------------------------------------------------
// Reduce K-split partials + bias(es) + optional ReLU.  Y is [32][O] row-major.
// ---------------------------------------------------------------------------
__global__ __launch_bounds__(256) void reduce_bias(
    const float* __restrict__ partial, const float* __restrict__ bias1,
    const float* __restrict__ bias2, float* __restrict__ Y, int O, int relu,
    int ksplit)
{
    int idx = blockIdx.x * 256 + threadIdx.x;
    if (idx >= 32 * O) return;
    int b = idx / O, o = idx - b * O;
    float s = bias1[o] + (bias2 ? bias2[o] : 0.f);
    for (int k = 0; k < ksplit; k++)
        s += partial[((size_t)k * 32 + b) * O + o];
    Y[idx] = relu ? fmaxf(s, 0.f) : s;
}

// ---------------------------------------------------------------------------
// Fused per-pixel conv chain. One thread = one pixel. Weights are block-
// uniform (sample = blockIdx.y) -> scalar s_loads. The hidden vector h[64]
// lives in LDS (per-thread float4 slots, no barrier needed) so the register
// live-set stays ~60-80 VGPRs -> no scratch spills.
// ks layout per sample: k_in[64*32] | k_mid[64*64] | k_out[32*64] |
//                       k_short[32*32] | b_in[64] | b_mid[64] | b_out[32] | b_short[32]
// ---------------------------------------------------------------------------
__global__ __launch_bounds__(256, 2) void conv_fused(
    const float* __restrict__ x, const float* __restrict__ ks,
    float* __restrict__ out)
{
    __shared__ float4 hls[16][256];   // h[q] at hls[q>>2][t][q&3], 64 KB

    const int t = threadIdx.x;
    const int b = blockIdx.y;
    const int p = blockIdx.x * 256 + t;             // 0..16383
    const float* __restrict__ kb = ks + (size_t)b * KT;
    const float* __restrict__ xb = x + (size_t)b * 32 * 16384 + p;

    float xv[32];
#pragma unroll
    for (int i = 0; i < 32; i++) xv[i] = xb[(size_t)i * 16384];

    // ---- layer in: h = relu(k_in @ x + b_in), streamed to LDS in float4s
    for (int q4 = 0; q4 < 16; ++q4) {
        float4 hq;
        float* hqf = (float*)&hq;
#pragma unroll
        for (int j = 0; j < 4; ++j) {
            int oo = q4 * 4 + j;
            float a = kb[9216 + oo];
#pragma unroll
            for (int i = 0; i < 32; i++) a += kb[oo * 32 + i] * xv[i];
            hqf[j] = fmaxf(a, 0.f);
        }
        hls[q4][t] = hq;
    }

    // ---- shortcut + out-bias accumulators: o_ = k_short @ x + b_short + b_out
    float o_[32];
#pragma unroll
    for (int oo = 0; oo < 32; oo++) {
        float a = kb[9376 + oo] + kb[9344 + oo];
#pragma unroll
        for (int i = 0; i < 32; i++) a += kb[8192 + oo * 32 + i] * xv[i];
        o_[oo] = a;
    }

    // ---- mid layer (chunks of 8, h from LDS) fused into out accumulation
#pragma unroll 1
    for (int c = 0; c < 64; c += 8) {
        float m[8];
#pragma unroll
        for (int j = 0; j < 8; j++) m[j] = kb[9280 + c + j];
#pragma unroll 1
        for (int q4 = 0; q4 < 16; ++q4) {
            float4 hq = hls[q4][t];
            const float* hqf = (const float*)&hq;
#pragma unroll
            for (int j = 0; j < 8; j++)
#pragma unroll
                for (int e = 0; e < 4; ++e)
                    m[j] += kb[2048 + (c + j) * 64 + q4 * 4 + e] * hqf[e];
        }
#pragma unroll
        for (int j = 0; j < 8; j++) m[j] = fmaxf(m[j], 0.f);
#pragma unroll
        for (int oo = 0; oo < 32; oo++) {
            float a = o_[oo];
#pragma unroll
            for (int j = 0; j < 8; j++) a += kb[6144 + oo * 64 + c + j] * m[j];
            o_[oo] = a;
        }
    }

#pragma unroll
    for (int oo = 0; oo < 32; oo++)
        out[((size_t)b * 32 + oo) * 16384 + p] = o_[oo];
}

// ---------------------------------------------------------------------------
extern "C" void kernel_launch(void* const* d_in, const int* in_sizes, int n_in,
                              void* d_out, int out_size, void* d_ws, size_t ws_size,
                              hipStream_t stream)
{
    const float* x   = (const float*)d_in[0];
    const float* lat = (const float*)d_in[1];
    const float* w0  = (const float*)d_in[2];
    const float* b0  = (const float*)d_in[3];
    const float* w1a = (const float*)d_in[4];
    const float* b1a = (const float*)d_in[5];
    const float* w1b = (const float*)d_in[6];
    const float* b1b = (const float*)d_in[7];
    const float* w1s = (const float*)d_in[8];
    const float* b1s = (const float*)d_in[9];
    const float* w2a = (const float*)d_in[10];
    const float* b2a = (const float*)d_in[11];
    const float* w2b = (const float*)d_in[12];
    const float* b2b = (const float*)d_in[13];
    const float* w2s = (const float*)d_in[14];
    const float* b2s = (const float*)d_in[15];
    const float* wfa = (const float*)d_in[16];
    const float* bfa = (const float*)d_in[17];

    // intermediates in d_ws (~2.8 MB)
    float* ws  = (float*)d_ws;
    float* h0  = ws;               // 32*512
    float* t1  = ws + 16384;       // 32*1024
    float* h1  = ws + 49152;       // 32*512
    float* t2  = ws + 65536;       // 32*1024
    float* h2  = ws + 98304;       // 32*9408
    float* ksb = ws + 399360;      // 32*9408
    // K-split partials live in d_out (<=38.6 MB < 64 MB); conv overwrites at end.
    float* pbuf = (float*)d_out;

    dim3 blk(256);
    auto g  = [](int O, int ks) { return dim3((unsigned)((O + NT - 1) / NT), (unsigned)ks); };
    auto rg = [](int O) { return dim3((unsigned)((32 * O + 255) / 256)); };

    // h0 = lat @ w0.T + b0                      (K=512, split 32 -> chunk 16)
    gemm32_partial<<<g(512, 32), blk, 0, stream>>>(lat, w0, 512, nullptr, nullptr, 0, pbuf, 512, 32);
    reduce_bias<<<rg(512), blk, 0, stream>>>(pbuf, b0, nullptr, h0, 512, 0, 32);
    // t1 = relu(h0 @ w1a.T + b1a)               (K=512)
    gemm32_partial<<<g(1024, 32), blk, 0, stream>>>(h0, w1a, 512, nullptr, nullptr, 0, pbuf, 1024, 32);
    reduce_bias<<<rg(1024), blk, 0, stream>>>(pbuf, b1a, nullptr, t1, 1024, 1, 32);
    // h1 = h0 @ w1s.T + b1s + t1 @ w1b.T + b1b  (K=1536, split 32 -> chunk 48)
    gemm32_partial<<<g(512, 32), blk, 0, stream>>>(h0, w1s, 512, t1, w1b, 1024, pbuf, 512, 32);
    reduce_bias<<<rg(512), blk, 0, stream>>>(pbuf, b1s, b1b, h1, 512, 0, 32);
    // t2 = relu(h1 @ w2a.T + b2a)               (K=512)
    gemm32_partial<<<g(1024, 32), blk, 0, stream>>>(h1, w2a, 512, nullptr, nullptr, 0, pbuf, 1024, 32);
    reduce_bias<<<rg(1024), blk, 0, stream>>>(pbuf, b2a, nullptr, t2, 1024, 1, 32);
    // h2 = h1 @ w2s.T + b2s + t2 @ w2b.T + b2b  (K=1536, split 32 -> chunk 48)
    gemm32_partial<<<g(KT, 32), blk, 0, stream>>>(h1, w2s, 512, t2, w2b, 1024, pbuf, KT, 32);
    reduce_bias<<<rg(KT), blk, 0, stream>>>(pbuf, b2s, b2b, h2, KT, 0, 32);
    // ks = h2 @ wfa.T + bfa                     (K=9408, split 28 -> chunk 336)
    gemm32_partial<<<g(KT, 28), blk, 0, stream>>>(h2, wfa, KT, nullptr, nullptr, 0, pbuf, KT, 28);
    reduce_bias<<<rg(KT), blk, 0, stream>>>(pbuf, bfa, nullptr, ksb, KT, 0, 28);

    // fused per-sample 1x1 conv chain
    conv_fused<<<dim3(64, 32), blk, 0, stream>>>(x, ksb, (float*)d_out);
}

// Round 5
// 293.815 us; speedup vs baseline: 4.5815x; 2.0738x over previous
//
#include <hip/hip_runtime.h>
#include <cstdint>

#define KT 9408      // K_TOTAL
#define NT 256       // o-tile per block
#define KC 16        // k sub-chunk staged in LDS

// ---------------------------------------------------------------------------
// Partial GEMM:  partial[s][b][o] = sum_{k in split s} X[b,k] * W[o,k]
// (unchanged from R4 — no longer the bottleneck's top offender)
// ---------------------------------------------------------------------------
__global__ __launch_bounds__(256, 1) void gemm32_partial(
    const float* __restrict__ X1, const float* __restrict__ W1, int K1,
    const float* __restrict__ X2, const float* __restrict__ W2, int K2,
    float* __restrict__ partial, int O, int ksplit)
{
    __shared__ float Xs[KC][32];     // [k_local][b]
    __shared__ float Wt[KC][NT];     // [k_local][o_local] transposed

    const int t      = threadIdx.x;
    const int o0     = blockIdx.x * NT;
    const int s      = blockIdx.y;
    const int kchunk = (K1 + K2) / ksplit;     // multiple of KC
    const int kbeg   = s * kchunk;
    const int kend   = kbeg + kchunk;
    const int lane   = t & 63;
    const int wv     = t >> 6;                 // wave id -> b-group (8 b's)

    const int sr  = t >> 2;                    // 0..63  (+64*p)
    const int sc4 = (t & 3) << 2;              // 0,4,8,12

    float4 wpre[4];
    float  xpre[2];

    {
        int kc0 = kbeg;
#pragma unroll
        for (int p = 0; p < 4; ++p) {
            int r = sr + 64 * p;
            int o = o0 + r;
            int kg = kc0 + sc4;
            float4 v = make_float4(0.f, 0.f, 0.f, 0.f);
            if (o < O)
                v = (kg < K1) ? *(const float4*)&W1[(size_t)o * K1 + kg]
                              : *(const float4*)&W2[(size_t)o * K2 + (kg - K1)];
            wpre[p] = v;
        }
#pragma unroll
        for (int it = 0; it < 2; ++it) {
            int idx = t + 256 * it;
            int kg  = kc0 + (idx >> 5);
            int bb  = idx & 31;
            xpre[it] = (kg < K1) ? X1[(size_t)bb * K1 + kg]
                                 : X2[(size_t)bb * K2 + (kg - K1)];
        }
    }

    float acc[8][4];
#pragma unroll
    for (int bi = 0; bi < 8; bi++)
#pragma unroll
        for (int j = 0; j < 4; j++) acc[bi][j] = 0.f;

    for (int kc0 = kbeg; kc0 < kend; kc0 += KC) {
#pragma unroll
        for (int it = 0; it < 2; ++it) {
            int idx = t + 256 * it;
            Xs[idx >> 5][idx & 31] = xpre[it];
        }
#pragma unroll
        for (int p = 0; p < 4; ++p) {
            int r = sr + 64 * p;
            Wt[sc4 + 0][r] = wpre[p].x;
            Wt[sc4 + 1][r] = wpre[p].y;
            Wt[sc4 + 2][r] = wpre[p].z;
            Wt[sc4 + 3][r] = wpre[p].w;
        }
        __syncthreads();

        if (kc0 + KC < kend) {
            int kn = kc0 + KC;
#pragma unroll
            for (int p = 0; p < 4; ++p) {
                int r = sr + 64 * p;
                int o = o0 + r;
                int kg = kn + sc4;
                float4 v = make_float4(0.f, 0.f, 0.f, 0.f);
                if (o < O)
                    v = (kg < K1) ? *(const float4*)&W1[(size_t)o * K1 + kg]
                                  : *(const float4*)&W2[(size_t)o * K2 + (kg - K1)];
                wpre[p] = v;
            }
#pragma unroll
            for (int it = 0; it < 2; ++it) {
                int idx = t + 256 * it;
                int kg  = kn + (idx >> 5);
                int bb  = idx & 31;
                xpre[it] = (kg < K1) ? X1[(size_t)bb * K1 + kg]
                                     : X2[(size_t)bb * K2 + (kg - K1)];
            }
        }

#pragma unroll
        for (int c = 0; c < KC; c++) {
            float4 xa = *(const float4*)&Xs[c][wv * 8];       // wave-broadcast
            float4 xb = *(const float4*)&Xs[c][wv * 8 + 4];
            float xv[8] = {xa.x, xa.y, xa.z, xa.w, xb.x, xb.y, xb.z, xb.w};
            float w[4];
#pragma unroll
            for (int j = 0; j < 4; j++) w[j] = Wt[c][lane + 64 * j];
#pragma unroll
            for (int bi = 0; bi < 8; bi++)
#pragma unroll
                for (int j = 0; j < 4; j++) acc[bi][j] += xv[bi] * w[j];
        }
        __syncthreads();
    }

#pragma unroll
    for (int bi = 0; bi < 8; bi++) {
        int b = wv * 8 + bi;
#pragma unroll
        for (int j = 0; j < 4; j++) {
            int o = o0 + lane + 64 * j;
            if (o < O)
                partial[((size_t)s * 32 + b) * O + o] = acc[bi][j];
        }
    }
}

// ---------------------------------------------------------------------------
__global__ __launch_bounds__(256) void reduce_bias(
    const float* __restrict__ partial, const float* __restrict__ bias1,
    const float* __restrict__ bias2, float* __restrict__ Y, int O, int relu,
    int ksplit)
{
    int idx = blockIdx.x * 256 + threadIdx.x;
    if (idx >= 32 * O) return;
    int b = idx / O, o = idx - b * O;
    float s = bias1[o] + (bias2 ? bias2[o] : 0.f);
    for (int k = 0; k < ksplit; k++)
        s += partial[((size_t)k * 32 + b) * O + o];
    Y[idx] = relu ? fmaxf(s, 0.f) : s;
}

// ---------------------------------------------------------------------------
// MFMA conv chain. mfma_f32_16x16x32_bf16, A = weights [M x K], B = x/h/m
// [K x 16px], D layout (m89-verified): row = 4*(lane>>4)+reg, col = lane&15.
// Crucial identity: D layout == B layout (n = lane&15, k = 4*(lane>>4)+slot),
// so each layer's D frags pack straight into the next layer's B operand
// (relu + bf16 round) — zero LDS, zero cross-lane ops. A and B use the same
// (lane-group, slot)->k convention, so the contraction is correct for any
// hardware slot ordering. Weights/biases: 18 A-frags + 10 bias f32x4 loaded
// once per wave, reused over TPW pixel tiles. Biases enter as MFMA C-init.
// ---------------------------------------------------------------------------
typedef __attribute__((ext_vector_type(8))) short bf16x8;
typedef __attribute__((ext_vector_type(4))) float f32x4;

__device__ inline uint32_t pkbf(float lo, float hi) {   // 2 f32 -> packed bf16x2 (RNE)
    uint32_t a = __builtin_bit_cast(uint32_t, lo);
    uint32_t b = __builtin_bit_cast(uint32_t, hi);
    a = (a + 0x7FFFu + ((a >> 16) & 1u)) >> 16;
    b = (b + 0x7FFFu + ((b >> 16) & 1u)) & 0xFFFF0000u;
    return a | b;
}

#define MFMA16(a, b, c) __builtin_amdgcn_mfma_f32_16x16x32_bf16(a, b, c, 0, 0, 0)

#define TPW 16   // pixel tiles (16 px) per wave

__global__ __launch_bounds__(256, 3) void conv_mfma(
    const float* __restrict__ x, const float* __restrict__ ks,
    float* __restrict__ out)
{
    const int t  = threadIdx.x;
    const int b  = blockIdx.y;
    const int l  = t & 63;
    const int g  = l >> 4;         // lane group 0..3
    const int n  = l & 15;         // col (pixel-in-tile) / A row offset
    const int wid = blockIdx.x * 4 + (t >> 6);   // wave id in sample, 0..63

    const float* __restrict__ kb = ks + (size_t)b * KT;

    // ---- A-frag loader: W row-major [rows][ldw], frag rows row0..row0+15,
    //      k = k0 + 4g + {0..3} (slots 0-3) and +16 (slots 4-7).
    auto loadA = [&](const float* W, int ldw, int row0, int k0) -> bf16x8 {
        const float* p = W + (size_t)(row0 + n) * ldw + k0 + 4 * g;
        float4 lo = *(const float4*)p;
        float4 hi = *(const float4*)(p + 16);
        union { bf16x8 v; uint32_t u[4]; } r;
        r.u[0] = pkbf(lo.x, lo.y);
        r.u[1] = pkbf(lo.z, lo.w);
        r.u[2] = pkbf(hi.x, hi.y);
        r.u[3] = pkbf(hi.z, hi.w);
        return r.v;
    };
    auto loadBias = [&](int off) -> f32x4 {   // bias[off + row(l,r)], r=0..3
        float4 v = *(const float4*)&kb[off + 4 * g];
        f32x4 r; r[0] = v.x; r[1] = v.y; r[2] = v.z; r[3] = v.w;
        return r;
    };

    // ---- weights (persistent in VGPRs)
    bf16x8 ain[4], amid[4][2], aout[2][2], ashort[2];
#pragma unroll
    for (int rt = 0; rt < 4; ++rt) ain[rt] = loadA(kb, 32, 16 * rt, 0);
#pragma unroll
    for (int ot = 0; ot < 4; ++ot)
#pragma unroll
        for (int kf = 0; kf < 2; ++kf) amid[ot][kf] = loadA(kb + 2048, 64, 16 * ot, 32 * kf);
#pragma unroll
    for (int ot = 0; ot < 2; ++ot)
#pragma unroll
        for (int kf = 0; kf < 2; ++kf) aout[ot][kf] = loadA(kb + 6144, 64, 16 * ot, 32 * kf);
#pragma unroll
    for (int ot = 0; ot < 2; ++ot) ashort[ot] = loadA(kb + 8192, 32, 16 * ot, 0);

    // ---- biases as C-init frags
    f32x4 bin[4], bmid[4], bos[2];
#pragma unroll
    for (int rt = 0; rt < 4; ++rt) bin[rt] = loadBias(9216 + 16 * rt);
#pragma unroll
    for (int ot = 0; ot < 4; ++ot) bmid[ot] = loadBias(9280 + 16 * ot);
#pragma unroll
    for (int ot = 0; ot < 2; ++ot) {
        f32x4 a = loadBias(9344 + 16 * ot);   // b_out
        f32x4 c = loadBias(9376 + 16 * ot);   // b_short
#pragma unroll
        for (int r = 0; r < 4; ++r) a[r] += c[r];
        bos[ot] = a;
    }

    const float* __restrict__ xbase = x + (size_t)b * 524288 + (size_t)(4 * g) * 16384 + n;
    float* __restrict__ obase = out + (size_t)b * 524288 + (size_t)(4 * g) * 16384 + n;

#pragma unroll 1
    for (int it = 0; it < TPW; ++it) {
        const int px0 = (wid * TPW + it) * 16;

        // ---- B-frag of x: slot j -> ch = 4g + (j&3) + 16*(j>>2), px = px0+n
        const float* p = xbase + px0;
        float e0 = p[0], e1 = p[16384], e2 = p[2 * 16384], e3 = p[3 * 16384];
        const float* q = p + (size_t)16 * 16384;
        float e4 = q[0], e5 = q[16384], e6 = q[2 * 16384], e7 = q[3 * 16384];
        union { bf16x8 v; uint32_t u[4]; } bx;
        bx.u[0] = pkbf(e0, e1); bx.u[1] = pkbf(e2, e3);
        bx.u[2] = pkbf(e4, e5); bx.u[3] = pkbf(e6, e7);

        // ---- layer in: h = relu(k_in @ x + b_in)   (4 MFMAs)
        f32x4 h[4];
#pragma unroll
        for (int rt = 0; rt < 4; ++rt) {
            f32x4 acc = MFMA16(ain[rt], bx.v, bin[rt]);
#pragma unroll
            for (int r = 0; r < 4; ++r) acc[r] = fmaxf(acc[r], 0.f);
            h[rt] = acc;
        }
        union { bf16x8 v; uint32_t u[4]; } hb0, hb1;
        hb0.u[0] = pkbf(h[0][0], h[0][1]); hb0.u[1] = pkbf(h[0][2], h[0][3]);
        hb0.u[2] = pkbf(h[1][0], h[1][1]); hb0.u[3] = pkbf(h[1][2], h[1][3]);
        hb1.u[0] = pkbf(h[2][0], h[2][1]); hb1.u[1] = pkbf(h[2][2], h[2][3]);
        hb1.u[2] = pkbf(h[3][0], h[3][1]); hb1.u[3] = pkbf(h[3][2], h[3][3]);

        // ---- layer mid: m = relu(k_mid @ h + b_mid)  (8 MFMAs)
        f32x4 m[4];
#pragma unroll
        for (int ot = 0; ot < 4; ++ot) {
            f32x4 acc = MFMA16(amid[ot][0], hb0.v, bmid[ot]);
            acc = MFMA16(amid[ot][1], hb1.v, acc);
#pragma unroll
            for (int r = 0; r < 4; ++r) acc[r] = fmaxf(acc[r], 0.f);
            m[ot] = acc;
        }
        union { bf16x8 v; uint32_t u[4]; } mb0, mb1;
        mb0.u[0] = pkbf(m[0][0], m[0][1]); mb0.u[1] = pkbf(m[0][2], m[0][3]);
        mb0.u[2] = pkbf(m[1][0], m[1][1]); mb0.u[3] = pkbf(m[1][2], m[1][3]);
        mb1.u[0] = pkbf(m[2][0], m[2][1]); mb1.u[1] = pkbf(m[2][2], m[2][3]);
        mb1.u[2] = pkbf(m[3][0], m[3][1]); mb1.u[3] = pkbf(m[3][2], m[3][3]);

        // ---- out: y = k_out @ m + k_short @ x + (b_out+b_short)  (6 MFMAs)
#pragma unroll
        for (int ot = 0; ot < 2; ++ot) {
            f32x4 acc = MFMA16(ashort[ot], bx.v, bos[ot]);
            acc = MFMA16(aout[ot][0], mb0.v, acc);
            acc = MFMA16(aout[ot][1], mb1.v, acc);
            float* po = obase + (size_t)(16 * ot) * 16384 + px0;
            po[0]         = acc[0];
            po[16384]     = acc[1];
            po[2 * 16384] = acc[2];
            po[3 * 16384] = acc[3];
        }
    }
}

// ---------------------------------------------------------------------------
extern "C" void kernel_launch(void* const* d_in, const int* in_sizes, int n_in,
                              void* d_out, int out_size, void* d_ws, size_t ws_size,
                              hipStream_t stream)
{
    const float* x   = (const float*)d_in[0];
    const float* lat = (const float*)d_in[1];
    const float* w0  = (const float*)d_in[2];
    const float* b0  = (const float*)d_in[3];
    const float* w1a = (const float*)d_in[4];
    const float* b1a = (const float*)d_in[5];
    const float* w1b = (const float*)d_in[6];
    const float* b1b = (const float*)d_in[7];
    const float* w1s = (const float*)d_in[8];
    const float* b1s = (const float*)d_in[9];
    const float* w2a = (const float*)d_in[10];
    const float* b2a = (const float*)d_in[11];
    const float* w2b = (const float*)d_in[12];
    const float* b2b = (const float*)d_in[13];
    const float* w2s = (const float*)d_in[14];
    const float* b2s = (const float*)d_in[15];
    const float* wfa = (const float*)d_in[16];
    const float* bfa = (const float*)d_in[17];

    // intermediates in d_ws (~2.8 MB)
    float* ws  = (float*)d_ws;
    float* h0  = ws;               // 32*512
    float* t1  = ws + 16384;       // 32*1024
    float* h1  = ws + 49152;       // 32*512
    float* t2  = ws + 65536;       // 32*1024
    float* h2  = ws + 98304;       // 32*9408
    float* ksb = ws + 399360;      // 32*9408
    // K-split partials live in d_out (<=38.6 MB < 64 MB); conv overwrites at end.
    float* pbuf = (float*)d_out;

    dim3 blk(256);
    auto g  = [](int O, int ks) { return dim3((unsigned)((O + NT - 1) / NT), (unsigned)ks); };
    auto rg = [](int O) { return dim3((unsigned)((32 * O + 255) / 256)); };

    gemm32_partial<<<g(512, 32), blk, 0, stream>>>(lat, w0, 512, nullptr, nullptr, 0, pbuf, 512, 32);
    reduce_bias<<<rg(512), blk, 0, stream>>>(pbuf, b0, nullptr, h0, 512, 0, 32);
    gemm32_partial<<<g(1024, 32), blk, 0, stream>>>(h0, w1a, 512, nullptr, nullptr, 0, pbuf, 1024, 32);
    reduce_bias<<<rg(1024), blk, 0, stream>>>(pbuf, b1a, nullptr, t1, 1024, 1, 32);
    gemm32_partial<<<g(512, 32), blk, 0, stream>>>(h0, w1s, 512, t1, w1b, 1024, pbuf, 512, 32);
    reduce_bias<<<rg(512), blk, 0, stream>>>(pbuf, b1s, b1b, h1, 512, 0, 32);
    gemm32_partial<<<g(1024, 32), blk, 0, stream>>>(h1, w2a, 512, nullptr, nullptr, 0, pbuf, 1024, 32);
    reduce_bias<<<rg(1024), blk, 0, stream>>>(pbuf, b2a, nullptr, t2, 1024, 1, 32);
    gemm32_partial<<<g(KT, 32), blk, 0, stream>>>(h1, w2s, 512, t2, w2b, 1024, pbuf, KT, 32);
    reduce_bias<<<rg(KT), blk, 0, stream>>>(pbuf, b2s, b2b, h2, KT, 0, 32);
    gemm32_partial<<<g(KT, 28), blk, 0, stream>>>(h2, wfa, KT, nullptr, nullptr, 0, pbuf, KT, 28);
    reduce_bias<<<rg(KT), blk, 0, stream>>>(pbuf, bfa, nullptr, ksb, KT, 0, 28);

    // MFMA conv chain: grid (16 px-blocks, 32 samples), 4 waves/block, 16 tiles/wave
    conv_mfma<<<dim3(16, 32), blk, 0, stream>>>(x, ksb, (float*)d_out);
}